// Round 11
// baseline (303.173 us; speedup 1.0000x reference)
//
#include <hip/hip_runtime.h>
#include <math.h>

#define SS 4096   // S = H*W
#define CC 256    // channels
#define NB 2      // batch
#define KSPLIT 8  // key chunks per head
#define KCHUNK (SS / KSPLIT)   // 512
#define KT 64     // key tile
#define QTM 64    // queries per block (4 waves x 16)

typedef __bf16 bf16x8 __attribute__((ext_vector_type(8)));
typedef float f32x4 __attribute__((ext_vector_type(4)));

__device__ inline float b2f(unsigned short u) {
    union { float f; unsigned int i; } x; x.i = ((unsigned int)u) << 16; return x.f;
}

// v_exp_f32 is base-2: D = 2^S0  (cdna4_isa.md §3). Avoids glibc __exp2f clash.
__device__ inline float fast_exp2(float x) { return __builtin_amdgcn_exp2f(x); }

// ---------------------------------------------------------------------------
// 0) Fused setup: [0,2048) transpose x->xT; [2048,2304) f1w->bf16;
//    [2304,2560) f2w->bf16; [2560,2564) pack per-head attention weights.
//    Wall[h][96][64] bf16 = [QSC*qlw@qw | klw@kw | vw]; QSC folds 1/sqrt(16)*log2e.
// ---------------------------------------------------------------------------
__global__ __launch_bounds__(256) void setup_kernel(
    const float* __restrict__ x,
    const float* __restrict__ qw, const float* __restrict__ qb,
    const float* __restrict__ kw, const float* __restrict__ kb,
    const float* __restrict__ vw, const float* __restrict__ vb,
    const float* __restrict__ qlw, const float* __restrict__ klw,
    const float* __restrict__ f1w, const float* __restrict__ f2w,
    float* __restrict__ xT, __bf16* __restrict__ f1wb, __bf16* __restrict__ f2wb,
    __bf16* __restrict__ Wall, float* __restrict__ bias_all)
{
    __shared__ float tile[32][33];
    const int blk = blockIdx.x;
    const int t = threadIdx.x;

    if (blk < 2048) {
        // transpose x [B,C,S] -> xT [B,S,C]; 32x32 tile
        int b = blk >> 10;
        int rem = blk & 1023;
        int s0 = (rem & 127) * 32;
        int c0 = (rem >> 7) * 32;
        int tx = t & 31, ty = t >> 5;   // 32 x 8
        const float* xb = x + (size_t)b * CC * SS;
        for (int j = 0; j < 4; ++j)
            tile[ty + 8 * j][tx] = xb[(size_t)(c0 + ty + 8 * j) * SS + s0 + tx];
        __syncthreads();
        float* xTb = xT + (size_t)b * SS * CC;
        for (int j = 0; j < 4; ++j)
            xTb[(size_t)(s0 + ty + 8 * j) * CC + c0 + tx] = tile[tx][ty + 8 * j];
    } else if (blk < 2560) {
        // fp32 -> bf16 weight conversion (262144 elements each)
        const float* src = (blk < 2304) ? f1w : f2w;
        __bf16* dst = (blk < 2304) ? f1wb : f2wb;
        int base = (blk < 2304) ? (blk - 2048) : (blk - 2304);
        int i = (base * 256 + t) * 4;
        float4 v = *(const float4*)&src[i];
        union { uint2 u; __bf16 b[4]; } pk;
        pk.b[0] = (__bf16)v.x; pk.b[1] = (__bf16)v.y;
        pk.b[2] = (__bf16)v.z; pk.b[3] = (__bf16)v.w;
        *(uint2*)&dst[i] = pk.u;
    } else {
        // per-head weight pack
        const float QSC = 0.25f * 1.44269504088896340736f;
        int i = blk - 2560;   // head
        for (int idx = t; idx < 16 * 64; idx += 256) {
            int r = idx >> 6, c = idx & 63;
            float sq = 0.f, sk = 0.f;
            for (int j = 0; j < 64; ++j) {
                sq += qlw[(i * 16 + r) * 64 + j] * qw[(i * 64 + j) * 64 + c];
                sk += klw[(i * 16 + r) * 64 + j] * kw[(i * 64 + j) * 64 + c];
            }
            Wall[i * 6144 + idx] = (__bf16)(QSC * sq);
            Wall[i * 6144 + 1024 + idx] = (__bf16)sk;
        }
        for (int idx = t; idx < 64 * 64; idx += 256)
            Wall[i * 6144 + 2048 + idx] = (__bf16)vw[i * 4096 + idx];
        if (t < 16) {
            float sq = 0.f, sk = 0.f;
            for (int j = 0; j < 64; ++j) {
                sq += qlw[(i * 16 + t) * 64 + j] * qb[i * 64 + j];
                sk += klw[(i * 16 + t) * 64 + j] * kb[i * 64 + j];
            }
            bias_all[i * 96 + t] = QSC * sq;
            bias_all[i * 96 + 16 + t] = sk;
        }
        if (t < 64) bias_all[i * 96 + 32 + t] = vb[i * 64 + t];
    }
}

// ---------------------------------------------------------------------------
// 2) MFMA head projection for head 0 only (no prev-head input)
// ---------------------------------------------------------------------------
__global__ __launch_bounds__(256) void head_qkv_mfma_kernel(
    const float* __restrict__ xT,
    const __bf16* __restrict__ Wall, const float* __restrict__ bias_all,
    __bf16* __restrict__ Qlb, __bf16* __restrict__ Klb, __bf16* __restrict__ Vtb)
{
    __shared__ __align__(16) __bf16 sXi[32 * 72];
    __shared__ __align__(16) __bf16 sW[96 * 72];
    __shared__ __align__(16) __bf16 sVtT[64 * 40];
    __shared__ float sBias[96];

    const int t = threadIdx.x;
    const int b = blockIdx.y;
    const int s0 = blockIdx.x * 32;
    const int lane = t & 63, wv = t >> 6;
    const int wm = wv & 1, wnh = wv >> 1;
    const int c = lane & 15, g = lane >> 4;

    #pragma unroll
    for (int i = 0; i < 6; ++i) {
        int e = t + i * 256;
        int row = e >> 4, c4 = (e & 15) * 4;
        *(uint2*)&sW[row * 72 + c4] = *(const uint2*)&Wall[row * 64 + c4];
    }
    if (t < 96) sBias[t] = bias_all[t];

    #pragma unroll
    for (int i = 0; i < 2; ++i) {
        int idx = t + i * 256;
        int row = idx >> 4, c4 = (idx & 15) * 4;
        size_t grow = (size_t)(b * SS + s0 + row);
        float4 v = *(const float4*)&xT[grow * CC + c4];
        union { uint2 u; __bf16 bb[4]; } pk;
        pk.bb[0] = (__bf16)v.x; pk.bb[1] = (__bf16)v.y;
        pk.bb[2] = (__bf16)v.z; pk.bb[3] = (__bf16)v.w;
        *(uint2*)&sXi[row * 72 + c4] = pk.u;
    }
    __syncthreads();

    bf16x8 aX0 = *(const bf16x8*)&sXi[(wm * 16 + c) * 72 + g * 8];
    bf16x8 aX1 = *(const bf16x8*)&sXi[(wm * 16 + c) * 72 + 32 + g * 8];

    #pragma unroll
    for (int nt = 0; nt < 3; ++nt) {
        int ntile = wnh * 3 + nt;
        bf16x8 bW0 = *(const bf16x8*)&sW[(ntile * 16 + c) * 72 + g * 8];
        bf16x8 bW1 = *(const bf16x8*)&sW[(ntile * 16 + c) * 72 + 32 + g * 8];
        f32x4 d;
        #pragma unroll
        for (int r = 0; r < 4; ++r) d[r] = 0.f;
        d = __builtin_amdgcn_mfma_f32_16x16x32_bf16(aX0, bW0, d, 0, 0, 0);
        d = __builtin_amdgcn_mfma_f32_16x16x32_bf16(aX1, bW1, d, 0, 0, 0);

        int ch = ntile * 16 + c;
        float bb = sBias[ch];
        int srow_l0 = wm * 16 + g * 4;
        #pragma unroll
        for (int r = 0; r < 4; ++r) {
            float v = d[r] + bb;
            int srow = s0 + srow_l0 + r;
            if (ntile == 0)      Qlb[((size_t)b * SS + srow) * 16 + ch] = (__bf16)v;
            else if (ntile == 1) Klb[((size_t)b * SS + srow) * 16 + (ch - 16)] = (__bf16)v;
            else                 sVtT[(ch - 32) * 40 + srow_l0 + r] = (__bf16)v;
        }
    }
    __syncthreads();
    {
        int ch = t >> 2, chunk = t & 3;
        *(uint4*)&Vtb[((size_t)b * 64 + ch) * SS + s0 + chunk * 8] =
            *(const uint4*)&sVtT[ch * 40 + chunk * 8];
    }
}

// ---------------------------------------------------------------------------
// 3a) MFMA flash attention partials. Max-free exp2 softmax, deferred l,
//     dbuf K/V LDS, reg-prefetch, setprio. 256 thr = 4 waves x 16 q.
//     Grid 1024 blocks -> 3 blocks/CU (LDS 47KB), 12 waves/CU.
// ---------------------------------------------------------------------------
__global__ __launch_bounds__(256) void attn_mfma_kernel(
    const __bf16* __restrict__ Qlb, const __bf16* __restrict__ Klb,
    const __bf16* __restrict__ Vtb,
    __bf16* __restrict__ pacc, float* __restrict__ pl)
{
    __shared__ __align__(16) __bf16 sK[2][64 * 24];   // [k][r], 48B rows (32B used)
    __shared__ __align__(16) __bf16 sVt[2][64 * 64];  // [c][k], XOR-swizzled
    __shared__ __align__(16) __bf16 sP[4][16 * 64];   // per-wave [q][k], XOR-swizzled

    const int t = threadIdx.x;
    const int lane = t & 63, wv = t >> 6;
    const int b = blockIdx.z, chunk = blockIdx.y;
    const int g = lane >> 4, qi = lane & 15;
    const int qrow = blockIdx.x * QTM + wv * 16 + qi;

    bf16x8 bQ;
    #pragma unroll
    for (int j = 0; j < 8; ++j) bQ[j] = (__bf16)0.f;
    if (lane < 32) bQ = *(const bf16x8*)(Qlb + ((size_t)b * SS + qrow) * 16 + g * 8);

    f32x4 acc[4];
    #pragma unroll
    for (int cs = 0; cs < 4; ++cs)
        #pragma unroll
        for (int r = 0; r < 4; ++r) acc[cs][r] = 0.f;
    float lpart = 0.f;

    __bf16* Pw = &sP[wv][0];
    const size_t kbase = (size_t)b * SS;
    const int kbeg = chunk * KCHUNK;
    const int kend = kbeg + KCHUNK;

    // staging: sK 256 uint2 (1/thr); sVt 512 uint4 (2/thr: rows svc and svc+32)
    const int skk = t >> 2, squad = t & 3;
    const int svc = t >> 3, svsl = t & 7;
    const int svsrc = (svsl ^ (svc & 7)) * 8;   // (svc+32)&7 == svc&7: same swizzle

    uint2 rK;
    uint4 rV0, rV1;
    rK  = *(const uint2*)(Klb + (kbase + kbeg + skk) * 16 + squad * 4);
    rV0 = *(const uint4*)(Vtb + ((size_t)b * 64 + svc) * SS + kbeg + svsrc);
    rV1 = *(const uint4*)(Vtb + ((size_t)b * 64 + svc + 32) * SS + kbeg + svsrc);
    *(uint2*)((char*)&sK[0][0] + skk * 48 + squad * 8) = rK;
    *(uint4*)((char*)&sVt[0][0] + svc * 128 + svsl * 16) = rV0;
    *(uint4*)((char*)&sVt[0][0] + (svc + 32) * 128 + svsl * 16) = rV1;
    __syncthreads();

    int cur = 0;
    for (int kt0 = kbeg; kt0 < kend; kt0 += KT) {
        const bool more = (kt0 + KT) < kend;
        if (more) {
            rK  = *(const uint2*)(Klb + (kbase + kt0 + KT + skk) * 16 + squad * 4);
            rV0 = *(const uint4*)(Vtb + ((size_t)b * 64 + svc) * SS + kt0 + KT + svsrc);
            rV1 = *(const uint4*)(Vtb + ((size_t)b * 64 + svc + 32) * SS + kt0 + KT + svsrc);
        }
        const char* sKc = (const char*)&sK[cur][0];
        const char* sVc = (const char*)&sVt[cur][0];

        // QK^T swapped (log2-domain scores; Q pre-scaled)
        f32x4 st[4];
        __builtin_amdgcn_s_setprio(1);
        #pragma unroll
        for (int ks = 0; ks < 4; ++ks) {
            bf16x8 aK;
            #pragma unroll
            for (int j = 0; j < 8; ++j) aK[j] = (__bf16)0.f;
            if (lane < 32)
                aK = *(const bf16x8*)(sKc + (ks * 16 + qi) * 48 + g * 16);
            f32x4 z;
            #pragma unroll
            for (int r = 0; r < 4; ++r) z[r] = 0.f;
            st[ks] = __builtin_amdgcn_mfma_f32_16x16x32_bf16(aK, bQ, z, 0, 0, 0);
        }
        __builtin_amdgcn_s_setprio(0);

        // max-free softmax: p = 2^s directly
        #pragma unroll
        for (int ks = 0; ks < 4; ++ks) {
            union { uint2 u; __bf16 bb[4]; } pk;
            #pragma unroll
            for (int r = 0; r < 4; ++r) {
                float p = fast_exp2(st[ks][r]);
                lpart += p;
                pk.bb[r] = (__bf16)p;
            }
            int off = (qi * 128 + ks * 32 + g * 8) ^ ((qi & 7) << 4);
            *(uint2*)((char*)Pw + off) = pk.u;
        }

        __builtin_amdgcn_s_setprio(1);
        #pragma unroll
        for (int kc = 0; kc < 2; ++kc) {
            int boff = (qi * 128 + kc * 64 + g * 16) ^ ((qi & 7) << 4);
            bf16x8 bP = *(const bf16x8*)((char*)Pw + boff);
            #pragma unroll
            for (int cs = 0; cs < 4; ++cs) {
                int c = cs * 16 + qi;
                int aoff = (c * 128 + kc * 64 + g * 16) ^ ((c & 7) << 4);
                bf16x8 aV = *(const bf16x8*)(sVc + aoff);
                acc[cs] = __builtin_amdgcn_mfma_f32_16x16x32_bf16(aV, bP, acc[cs], 0, 0, 0);
            }
        }
        __builtin_amdgcn_s_setprio(0);

        if (more) {
            *(uint2*)((char*)&sK[cur ^ 1][0] + skk * 48 + squad * 8) = rK;
            *(uint4*)((char*)&sVt[cur ^ 1][0] + svc * 128 + svsl * 16) = rV0;
            *(uint4*)((char*)&sVt[cur ^ 1][0] + (svc + 32) * 128 + svsl * 16) = rV1;
            __syncthreads();
            cur ^= 1;
        }
    }

    lpart += __shfl_xor(lpart, 16);
    lpart += __shfl_xor(lpart, 32);

    size_t prow = (size_t)(b * KSPLIT + chunk) * SS + qrow;
    #pragma unroll
    for (int cs = 0; cs < 4; ++cs) {
        union { uint2 u; __bf16 bb[4]; } pk;
        #pragma unroll
        for (int r = 0; r < 4; ++r) pk.bb[r] = (__bf16)acc[cs][r];
        *(uint2*)(pacc + prow * 64 + cs * 16 + g * 4) = pk.u;
    }
    if (lane < 16) pl[prow] = lpart;
}

// ---------------------------------------------------------------------------
// 3b) Fused: combine(head) + BN1 stats + qkv(head+1) MFMA (if head<3)
//     Max-free partials: merge is a plain sum. conc stored bf16.
// ---------------------------------------------------------------------------
__global__ __launch_bounds__(512) void combine_qkv_kernel(
    const __bf16* __restrict__ pacc, const float* __restrict__ pl,
    const float* __restrict__ ow, const float* __restrict__ ob,
    const float* __restrict__ xT, const __bf16* __restrict__ Wall,
    const float* __restrict__ bias_all,
    __bf16* __restrict__ concb, float* __restrict__ gsum, float* __restrict__ gss,
    __bf16* __restrict__ Qlb, __bf16* __restrict__ Klb, __bf16* __restrict__ Vtb, int head)
{
    __shared__ float sO[32][66];
    __shared__ float sOWt[64][68];
    __shared__ float sob[64];
    __shared__ float lsum[64], lss[64];
    __shared__ __align__(16) __bf16 sXi[32 * 72];
    __shared__ __align__(16) __bf16 sW[96 * 72];
    __shared__ __align__(16) __bf16 sVtT[64 * 40];
    __shared__ float sBias[96];

    const int t = threadIdx.x;
    const int b = blockIdx.y;
    const int s0 = blockIdx.x * 32;
    const int q = t >> 4;
    const int gk = t & 15;
    const int vc0 = gk * 4;
    const int nexth = head + 1;

    if (t < 64) { lsum[t] = 0.f; lss[t] = 0.f; }
    for (int idx = t; idx < 4096; idx += 512) {
        int co = idx >> 6, k = idx & 63;
        sOWt[k][co] = ow[head * 4096 + idx];
    }
    if (t < 64) sob[t] = ob[head * 64 + t];
    if (head < 3) {
        #pragma unroll
        for (int i = 0; i < 3; ++i) {
            int e = t + i * 512;
            int row = e >> 4, c4 = (e & 15) * 4;
            *(uint2*)&sW[row * 72 + c4] = *(const uint2*)&Wall[nexth * 6144 + row * 64 + c4];
        }
        if (t < 96) sBias[t] = bias_all[nexth * 96 + t];
    }

    // merge KSPLIT partials: plain sum
    float l = 0.f;
    float o0 = 0.f, o1 = 0.f, o2 = 0.f, o3 = 0.f;
    const unsigned short* pu = (const unsigned short*)pacc;
    #pragma unroll
    for (int c = 0; c < KSPLIT; ++c) {
        size_t prow = (size_t)(b * KSPLIT + c) * SS + s0 + q;
        l += pl[prow];
        ushort4 a4 = *(const ushort4*)&pu[prow * 64 + vc0];
        o0 += b2f(a4.x); o1 += b2f(a4.y); o2 += b2f(a4.z); o3 += b2f(a4.w);
    }
    float inv_l = 1.f / l;
    sO[q][vc0 + 0] = o0 * inv_l;
    sO[q][vc0 + 1] = o1 * inv_l;
    sO[q][vc0 + 2] = o2 * inv_l;
    sO[q][vc0 + 3] = o3 * inv_l;
    __syncthreads();

    // epilogue: out = ob + O @ ow^T
    float e[4];
    #pragma unroll
    for (int j = 0; j < 4; ++j) e[j] = sob[vc0 + j];
    #pragma unroll 8
    for (int k = 0; k < 64; ++k) {
        float ov = sO[q][k];
        float4 w4 = *(const float4*)&sOWt[k][vc0];
        e[0] += ov * w4.x; e[1] += ov * w4.y; e[2] += ov * w4.z; e[3] += ov * w4.w;
    }
    {
        union { uint2 u; __bf16 bb[4]; } pk;
        pk.bb[0] = (__bf16)e[0]; pk.bb[1] = (__bf16)e[1];
        pk.bb[2] = (__bf16)e[2]; pk.bb[3] = (__bf16)e[3];
        *(uint2*)&concb[((size_t)(b * SS + s0 + q)) * CC + head * 64 + vc0] = pk.u;
    }

    // BN1 stats (LDS accumulate)
    float sv[4], sq2[4];
    #pragma unroll
    for (int j = 0; j < 4; ++j) { sv[j] = e[j]; sq2[j] = e[j] * e[j]; }
    #pragma unroll
    for (int j = 0; j < 4; ++j) {
        sv[j] += __shfl_xor(sv[j], 16); sv[j] += __shfl_xor(sv[j], 32);
        sq2[j] += __shfl_xor(sq2[j], 16); sq2[j] += __shfl_xor(sq2[j], 32);
    }
    if ((t & 48) == 0) {
        #pragma unroll
        for (int j = 0; j < 4; ++j) {
            atomicAdd(&lsum[vc0 + j], sv[j]);
            atomicAdd(&lss[vc0 + j], sq2[j]);
        }
    }

    // next-head xi = xT[:, nexth*64:] + e  -> sXi (bf16)
    if (head < 3) {
        size_t grow = (size_t)(b * SS + s0 + q);
        float4 xv = *(const float4*)&xT[grow * CC + nexth * 64 + vc0];
        union { uint2 u; __bf16 bb[4]; } pk;
        pk.bb[0] = (__bf16)(xv.x + e[0]);
        pk.bb[1] = (__bf16)(xv.y + e[1]);
        pk.bb[2] = (__bf16)(xv.z + e[2]);
        pk.bb[3] = (__bf16)(xv.w + e[3]);
        *(uint2*)&sXi[q * 72 + vc0] = pk.u;
    }
    __syncthreads();

    if (t < 64) {
        atomicAdd(&gsum[head * 64 + t], lsum[t]);
        atomicAdd(&gss[head * 64 + t], lss[t]);
    }

    if (head < 3) {
        const int lane = t & 63, wv = t >> 6;
        const int wm = wv & 1, wn = wv >> 1;   // 2 m-tiles x 4 n-slots
        const int c = lane & 15, g = lane >> 4;

        bf16x8 aX0 = *(const bf16x8*)&sXi[(wm * 16 + c) * 72 + g * 8];
        bf16x8 aX1 = *(const bf16x8*)&sXi[(wm * 16 + c) * 72 + 32 + g * 8];

        #pragma unroll
        for (int ni = 0; ni < 2; ++ni) {
            int ntile = wn + ni * 4;
            if (ntile < 6) {
                bf16x8 bW0 = *(const bf16x8*)&sW[(ntile * 16 + c) * 72 + g * 8];
                bf16x8 bW1 = *(const bf16x8*)&sW[(ntile * 16 + c) * 72 + 32 + g * 8];
                f32x4 d;
                #pragma unroll
                for (int r = 0; r < 4; ++r) d[r] = 0.f;
                d = __builtin_amdgcn_mfma_f32_16x16x32_bf16(aX0, bW0, d, 0, 0, 0);
                d = __builtin_amdgcn_mfma_f32_16x16x32_bf16(aX1, bW1, d, 0, 0, 0);

                int ch = ntile * 16 + c;
                float bb = sBias[ch];
                int srow_l0 = wm * 16 + g * 4;
                #pragma unroll
                for (int r = 0; r < 4; ++r) {
                    float v = d[r] + bb;
                    int srow = s0 + srow_l0 + r;
                    if (ntile == 0)      Qlb[((size_t)b * SS + srow) * 16 + ch] = (__bf16)v;
                    else if (ntile == 1) Klb[((size_t)b * SS + srow) * 16 + (ch - 16)] = (__bf16)v;
                    else                 sVtT[(ch - 32) * 40 + srow_l0 + r] = (__bf16)v;
                }
            }
        }
        __syncthreads();
        int ch = t >> 3, chunk = t & 7;
        *(uint2*)&Vtb[((size_t)b * 64 + ch) * SS + s0 + chunk * 4] =
            *(const uint2*)&sVtT[ch * 40 + chunk * 4];
    }
}

// ---------------------------------------------------------------------------
// 5) out1b = bf16(xT + BN(concb))
// ---------------------------------------------------------------------------
__global__ void bn_apply1_kernel(const float* __restrict__ xT, const __bf16* __restrict__ concb,
                                 const float* __restrict__ sum, const float* __restrict__ sumsq,
                                 const float* __restrict__ g, const float* __restrict__ bta,
                                 __bf16* __restrict__ out1b)
{
    size_t idx = (size_t)blockIdx.x * 256 + threadIdx.x;
    int c = threadIdx.x;
    float mean = sum[c] * (1.f / 8192.f);
    float var = sumsq[c] * (1.f / 8192.f) - mean * mean;
    float rstd = rsqrtf(var + 1e-5f);
    float cv = b2f(((const unsigned short*)concb)[idx]);
    float v = xT[idx] + (cv - mean) * rstd * g[c] + bta[c];
    out1b[idx] = (__bf16)v;
}

// ---------------------------------------------------------------------------
// 6a) MFMA GEMM1: h1b = bf16(gelu(out1b @ f1w^T + b))
// ---------------------------------------------------------------------------
__global__ __launch_bounds__(256) void gemm1_mfma_kernel(
    const __bf16* __restrict__ A, const __bf16* __restrict__ W,
    const float* __restrict__ bias, __bf16* __restrict__ out, int N, int K)
{
    constexpr int MREP = 4;
    constexpr int BM = 2 * MREP * 16;
    __shared__ __align__(16) __bf16 sA[BM * 72];
    __shared__ __align__(16) __bf16 sB[64 * 72];

    const int t = threadIdx.x;
    const int lane = t & 63, wv = t >> 6;
    const int wm = wv & 1, wn = wv >> 1;
    const int g = lane >> 4, c = lane & 15;
    const int m0 = blockIdx.x * BM, n0 = blockIdx.y * 64;

    f32x4 acc[MREP][2];
    #pragma unroll
    for (int mi = 0; mi < MREP; ++mi)
        #pragma unroll
        for (int ni = 0; ni < 2; ++ni)
            #pragma unroll
            for (int r = 0; r < 4; ++r) acc[mi][ni][r] = 0.f;

    const int rS = t >> 3, ksS = (t & 7) * 8;

    for (int k0 = 0; k0 < K; k0 += 64) {
        __syncthreads();
        #pragma unroll
        for (int i = 0; i < MREP; ++i) {
            int r = rS + i * 32;
            *(uint4*)&sA[r * 72 + ksS] = *(const uint4*)&A[(size_t)(m0 + r) * K + k0 + ksS];
        }
        #pragma unroll
        for (int i = 0; i < 2; ++i) {
            int r = rS + i * 32;
            *(uint4*)&sB[r * 72 + ksS] = *(const uint4*)&W[(size_t)(n0 + r) * K + k0 + ksS];
        }
        __syncthreads();

        #pragma unroll
        for (int kk = 0; kk < 2; ++kk) {
            bf16x8 bfr[2];
            #pragma unroll
            for (int ni = 0; ni < 2; ++ni)
                bfr[ni] = *(const bf16x8*)&sB[(wn * 32 + ni * 16 + c) * 72 + kk * 32 + g * 8];
            #pragma unroll
            for (int mi = 0; mi < MREP; ++mi) {
                bf16x8 afr = *(const bf16x8*)&sA[(wm * MREP * 16 + mi * 16 + c) * 72 + kk * 32 + g * 8];
                #pragma unroll
                for (int ni = 0; ni < 2; ++ni)
                    acc[mi][ni] = __builtin_amdgcn_mfma_f32_16x16x32_bf16(afr, bfr[ni], acc[mi][ni], 0, 0, 0);
            }
        }
    }

    #pragma unroll
    for (int ni = 0; ni < 2; ++ni) {
        int col = n0 + wn * 32 + ni * 16 + c;
        float bb = bias[col];
        #pragma unroll
        for (int mi = 0; mi < MREP; ++mi) {
            int row0 = m0 + wm * MREP * 16 + mi * 16 + g * 4;
            #pragma unroll
            for (int r = 0; r < 4; ++r) {
                float v = acc[mi][ni][r] + bb;
                v = 0.5f * v * (1.f + erff(v * 0.70710678118654752f));
                out[(size_t)(row0 + r) * N + col] = (__bf16)v;
            }
        }
    }
}

// ---------------------------------------------------------------------------
// 6b) MFMA GEMM2 -> h2b bf16, fused BN2 stats
// ---------------------------------------------------------------------------
__global__ __launch_bounds__(256) void gemm2_mfma_stats_kernel(
    const __bf16* __restrict__ A, const __bf16* __restrict__ W,
    const float* __restrict__ bias, __bf16* __restrict__ out,
    float* __restrict__ gsum, float* __restrict__ gss, int N, int K)
{
    constexpr int MREP = 2;
    constexpr int BM = 2 * MREP * 16;
    __shared__ __align__(16) __bf16 sA[BM * 72];
    __shared__ __align__(16) __bf16 sB[64 * 72];
    __shared__ float lsum[64], lss[64];

    const int t = threadIdx.x;
    const int lane = t & 63, wv = t >> 6;
    const int wm = wv & 1, wn = wv >> 1;
    const int g = lane >> 4, c = lane & 15;
    const int m0 = blockIdx.x * BM, n0 = blockIdx.y * 64;

    if (t < 64) { lsum[t] = 0.f; lss[t] = 0.f; }

    f32x4 acc[MREP][2];
    #pragma unroll
    for (int mi = 0; mi < MREP; ++mi)
        #pragma unroll
        for (int ni = 0; ni < 2; ++ni)
            #pragma unroll
            for (int r = 0; r < 4; ++r) acc[mi][ni][r] = 0.f;

    const int rS = t >> 3, ksS = (t & 7) * 8;

    for (int k0 = 0; k0 < K; k0 += 64) {
        __syncthreads();
        #pragma unroll
        for (int i = 0; i < MREP; ++i) {
            int r = rS + i * 32;
            *(uint4*)&sA[r * 72 + ksS] = *(const uint4*)&A[(size_t)(m0 + r) * K + k0 + ksS];
        }
        #pragma unroll
        for (int i = 0; i < 2; ++i) {
            int r = rS + i * 32;
            *(uint4*)&sB[r * 72 + ksS] = *(const uint4*)&W[(size_t)(n0 + r) * K + k0 + ksS];
        }
        __syncthreads();

        #pragma unroll
        for (int kk = 0; kk < 2; ++kk) {
            bf16x8 bfr[2];
            #pragma unroll
            for (int ni = 0; ni < 2; ++ni)
                bfr[ni] = *(const bf16x8*)&sB[(wn * 32 + ni * 16 + c) * 72 + kk * 32 + g * 8];
            #pragma unroll
            for (int mi = 0; mi < MREP; ++mi) {
                bf16x8 afr = *(const bf16x8*)&sA[(wm * MREP * 16 + mi * 16 + c) * 72 + kk * 32 + g * 8];
                #pragma unroll
                for (int ni = 0; ni < 2; ++ni)
                    acc[mi][ni] = __builtin_amdgcn_mfma_f32_16x16x32_bf16(afr, bfr[ni], acc[mi][ni], 0, 0, 0);
            }
        }
    }

    #pragma unroll
    for (int ni = 0; ni < 2; ++ni) {
        int col = n0 + wn * 32 + ni * 16 + c;
        float bb = bias[col];
        float ps = 0.f, pss = 0.f;
        #pragma unroll
        for (int mi = 0; mi < MREP; ++mi) {
            int row0 = m0 + wm * MREP * 16 + mi * 16 + g * 4;
            #pragma unroll
            for (int r = 0; r < 4; ++r) {
                float v = acc[mi][ni][r] + bb;
                out[(size_t)(row0 + r) * N + col] = (__bf16)v;
                ps += v; pss += v * v;
            }
        }
        ps += __shfl_xor(ps, 16); ps += __shfl_xor(ps, 32);
        pss += __shfl_xor(pss, 16); pss += __shfl_xor(pss, 32);
        if ((t & 48) == 0) {
            atomicAdd(&lsum[wn * 32 + ni * 16 + c], ps);
            atomicAdd(&lss[wn * 32 + ni * 16 + c], pss);
        }
    }
    __syncthreads();
    if (t < 64) {
        atomicAdd(&gsum[n0 + t], lsum[t]);
        atomicAdd(&gss[n0 + t], lss[t]);
    }
}

// ---------------------------------------------------------------------------
// 7) final: d_out[b,c,s] = out1b[b,s,c] + BN(h2b)[b,s,c]
// ---------------------------------------------------------------------------
__global__ void bn_final_kernel(const __bf16* __restrict__ out1b, const __bf16* __restrict__ h2b,
                                const float* __restrict__ sum, const float* __restrict__ sumsq,
                                const float* __restrict__ g, const float* __restrict__ bta,
                                float* __restrict__ out)
{
    __shared__ float tile[32][33];
    int b = blockIdx.z;
    int s0 = blockIdx.x * 32, c0 = blockIdx.y * 32;
    int tx = threadIdx.x, ty = threadIdx.y;
    const unsigned short* o1 = (const unsigned short*)out1b;
    const unsigned short* h2 = (const unsigned short*)h2b;
    for (int j = 0; j < 4; ++j) {
        int c = c0 + tx;
        int s = s0 + ty + 8 * j;
        size_t idx = ((size_t)b * SS + s) * CC + c;
        float mean = sum[c] * (1.f / 8192.f);
        float var = sumsq[c] * (1.f / 8192.f) - mean * mean;
        float rstd = rsqrtf(var + 1e-5f);
        tile[ty + 8 * j][tx] = b2f(o1[idx]) + (b2f(h2[idx]) - mean) * rstd * g[c] + bta[c];
    }
    __syncthreads();
    for (int j = 0; j < 4; ++j) {
        int c = c0 + ty + 8 * j;
        int s = s0 + tx;
        out[((size_t)b * CC + c) * SS + s] = tile[tx][ty + 8 * j];
    }
}

// ---------------------------------------------------------------------------
extern "C" void kernel_launch(void* const* d_in, const int* in_sizes, int n_in,
                              void* d_out, int out_size, void* d_ws, size_t ws_size,
                              hipStream_t stream)
{
    const float* x   = (const float*)d_in[0];
    const float* qw  = (const float*)d_in[1];
    const float* qb  = (const float*)d_in[2];
    const float* kw  = (const float*)d_in[3];
    const float* kb  = (const float*)d_in[4];
    const float* vw  = (const float*)d_in[5];
    const float* vb  = (const float*)d_in[6];
    const float* qlw = (const float*)d_in[7];
    const float* klw = (const float*)d_in[8];
    const float* ow  = (const float*)d_in[9];
    const float* ob  = (const float*)d_in[10];
    const float* f1w = (const float*)d_in[11];
    const float* f1b = (const float*)d_in[12];
    const float* f2w = (const float*)d_in[13];
    const float* f2b = (const float*)d_in[14];
    const float* g1  = (const float*)d_in[15];
    const float* b1  = (const float*)d_in[16];
    const float* g2  = (const float*)d_in[17];
    const float* b2  = (const float*)d_in[18];
    float* outp = (float*)d_out;

    // workspace layout (floats; all offsets multiples of 64 floats)
    float* ws = (float*)d_ws;
    size_t off = 0;
    float* xT    = ws + off; off += (size_t)NB * SS * CC;
    __bf16* concb = (__bf16*)(ws + off); off += (size_t)NB * SS * CC / 2;
    float* Hreg  = ws + off; off += (size_t)NB * SS * 1024 / 2;
    __bf16* out1b = (__bf16*)(ws + off); off += (size_t)NB * SS * CC / 2;
    __bf16* h2b   = (__bf16*)(ws + off); off += (size_t)NB * SS * CC / 2;
    __bf16* Qlb  = (__bf16*)(ws + off); off += (size_t)NB * SS * 16 / 2;
    __bf16* Klb  = (__bf16*)(ws + off); off += (size_t)NB * SS * 16 / 2;
    __bf16* Vtb  = (__bf16*)(ws + off); off += (size_t)NB * 64 * SS / 2;
    __bf16* f1wb = (__bf16*)(ws + off); off += (size_t)1024 * CC / 2;
    __bf16* f2wb = (__bf16*)(ws + off); off += (size_t)CC * 1024 / 2;
    __bf16* Wall = (__bf16*)(ws + off); off += 4 * 6144 / 2;
    float* bias_all = ws + off; off += 4 * 96;
    float* stats = ws + off; off += 1024;
    float* sum1 = stats, *sumsq1 = stats + 256, *sum2 = stats + 512, *sumsq2 = stats + 768;

    // attention split-K partials alias Hreg (disjoint phases with h1b)
    __bf16* pacc = (__bf16*)Hreg;
    float* pl = Hreg + (size_t)NB * KSPLIT * SS * 64 / 2;
    __bf16* h1b = (__bf16*)Hreg;

    (void)hipMemsetAsync(stats, 0, 1024 * sizeof(float), stream);

    setup_kernel<<<2564, 256, 0, stream>>>(x, qw, qb, kw, kb, vw, vb, qlw, klw, f1w, f2w,
                                           xT, f1wb, f2wb, Wall, bias_all);

    head_qkv_mfma_kernel<<<dim3(SS / 32, NB), 256, 0, stream>>>(
        xT, Wall, bias_all, Qlb, Klb, Vtb);
    for (int head = 0; head < 4; ++head) {
        attn_mfma_kernel<<<dim3(SS / QTM, KSPLIT, NB), 256, 0, stream>>>(
            Qlb, Klb, Vtb, pacc, pl);
        combine_qkv_kernel<<<dim3(SS / 32, NB), 512, 0, stream>>>(
            pacc, pl, ow, ob, xT, Wall, bias_all,
            concb, sum1, sumsq1, Qlb, Klb, Vtb, head);
    }

    bn_apply1_kernel<<<(NB * SS * CC) / 256, 256, 0, stream>>>(
        xT, concb, sum1, sumsq1, g1, b1, out1b);

    gemm1_mfma_kernel<<<dim3((NB * SS) / 128, 1024 / 64), 256, 0, stream>>>(
        out1b, f1wb, f1b, h1b, 1024, CC);
    gemm2_mfma_stats_kernel<<<dim3((NB * SS) / 64, CC / 64), 256, 0, stream>>>(
        h1b, f2wb, f2b, h2b, sum2, sumsq2, CC, 1024);

    bn_final_kernel<<<dim3(SS / 32, CC / 32, NB), dim3(32, 8), 0, stream>>>(
        out1b, h2b, sum2, sumsq2, g2, b2, outp);
}